// Round 7
// baseline (1084.734 us; speedup 1.0000x reference)
//
#include <hip/hip_runtime.h>
#include <hip/hip_bf16.h>

// ---------------------------------------------------------------------------
// DenoiseGCN fused kernel for MI355X (gfx950) — round 7.
// R6 post-mortem: VALUBusy 48 / MfmaUtil 22 / Occ 42% — phase-lockstep +
// epilogue-VALU bound; bank conflicts 5e7 from scalar-b16 epilogue LDS ops.
// Fixes: (1) double-buffered h (hA/hB, 80KB LDS): 1 barrier/layer (was 2+),
// epilogue of wave X overlaps mm2-MFMA of wave Y (separate pipes);
// (2) packed-bf16 hreg residual (20 VGPR): kills 40 scalar ds_read + addr
// VALU per thread/layer (safe now: unroll-2 keeps weight hoisting bounded;
// tripwire = WRITE_SIZE balloon); (3) bias loads hoisted above mm2.
// ---------------------------------------------------------------------------

typedef __attribute__((ext_vector_type(8))) short bf16x8;
typedef __attribute__((ext_vector_type(4))) float f32x4;

#define NV 1024

// ws element offsets (bf16 elements)
#define OFF_W0T   0        // [256][160] merged: k<128 temb (W0+res0), 128-129 W0c, 130-131 res0c
#define OFF_W1T   40960    // [256][256], pre-scaled by 1/3
#define OFF_W2T   106496   // pre-scaled by 1/3
#define OFF_W3T   172032   // pre-scaled by 1/3
#define OFF_HW1T  237568
#define OFF_HW2T  303104   // [16][256]
#define OFF_TEMB  307200   // [512][128]
#define PREP_ELEMS 307200

__device__ __forceinline__ float bf2f(short u){
  union { unsigned int i; float f; } v;
  v.i = ((unsigned int)(unsigned short)u) << 16;
  return v.f;
}
__device__ __forceinline__ short f2bf(float f){
  __hip_bfloat16 h = __float2bfloat16(f);
  return *reinterpret_cast<short*>(&h);
}
__device__ __forceinline__ float silu_f(float v){
  float e = __expf(-v);
  return v * __builtin_amdgcn_rcpf(1.f + e);
}
__device__ __forceinline__ f32x4 zero4(){ f32x4 z = {0.f,0.f,0.f,0.f}; return z; }

// ---------------------------------------------------------------------------
// prep: fp32 weights -> bf16, transposed to [N][K] (k contiguous) with pads.
// W0T merged (see header). W1..W3 pre-scaled by 1/3 (agg commutes with W).
// ---------------------------------------------------------------------------
__global__ void prep_kernel(const float* __restrict__ W0, const float* __restrict__ res0,
                            const float* __restrict__ W1, const float* __restrict__ W2,
                            const float* __restrict__ W3, const float* __restrict__ hW1,
                            const float* __restrict__ hW2, short* __restrict__ ws){
  int idx = blockIdx.x * 256 + threadIdx.x;
  if (idx >= PREP_ELEMS) return;
  float v = 0.f;
  if (idx < 40960){
    int n = idx / 160, k = idx - n * 160;
    if (k < 128)      v = W0[(k + 2) * 256 + n] + res0[(k + 2) * 256 + n];
    else if (k < 130) v = W0[(k - 128) * 256 + n];
    else if (k < 132) v = res0[(k - 130) * 256 + n];
  } else if (idx < 303104){
    int rem = idx - 40960;
    int seg = rem >> 16;
    int r2 = rem & 65535;
    int n = r2 >> 8, k = r2 & 255;
    const float* src = (seg == 0) ? W1 : (seg == 1) ? W2 : (seg == 2) ? W3 : hW1;
    v = src[k * 256 + n];
    if (seg < 3) v *= (1.f / 3.f);
  } else {
    int rem = idx - 303104;
    int n = rem >> 8, k = rem & 255;
    if (n < 2) v = hW2[k * 2 + n];
  }
  ws[idx] = f2bf(v);
}

// ---------------------------------------------------------------------------
// temb: silu(sinusoidal(t) @ time_W + time_b) per batch element -> bf16
// ---------------------------------------------------------------------------
__global__ void temb_kernel(const int* __restrict__ t, const float* __restrict__ tW,
                            const float* __restrict__ tb, short* __restrict__ temb){
  __shared__ float sc[128];
  int b = blockIdx.x, n = threadIdx.x;  // 128 threads
  float tv = (float)t[b];
  {
    int j = n & 63;
    float fr = __expf(-9.210340371976184f * (float)j * (1.f / 63.f));
    float ang = tv * fr;
    sc[n] = (n < 64) ? sinf(ang) : cosf(ang);
  }
  __syncthreads();
  float acc = tb[n];
  #pragma unroll 8
  for (int k = 0; k < 128; ++k) acc += sc[k] * tW[k * 128 + n];
  temb[b * 128 + n] = f2bf(silu_f(acc));
}

// ---------------------------------------------------------------------------
// mm2: acc[mt][nt] += hbuf[80 x KPAD] @ Wt^T for this wave's 2 col-tiles.
// A-frag: row=l&15 (+16*mt), k=(l>>4)*8+j.  B-frag: col=l&15, same k.
// C: col=l&15, row=(l>>4)*4+j.  hbuf rows are 512B, XOR-swizzled per 16B chunk.
// unroll 2: caps in-flight weight fragments (full unroll spilled — R4).
// ---------------------------------------------------------------------------
template<int KPAD>
__device__ __forceinline__ void mm2(const char* hbuf, const short* __restrict__ Wt,
                                    int m15, int g, int n0, f32x4 acc[5][2]){
  const short* wb = Wt + (n0 + m15) * KPAD + g * 8;
  #pragma unroll 2
  for (int ks = 0; ks < KPAD / 32; ++ks){
    bf16x8 bf0 = *(const bf16x8*)(wb + ks * 32);
    bf16x8 bf1 = *(const bf16x8*)(wb + 16 * KPAD + ks * 32);
    const int kb = ks * 64 + g * 16;
    #pragma unroll
    for (int mt = 0; mt < 5; ++mt){
      const int row = mt * 16 + m15;
      bf16x8 a = *(const bf16x8*)(hbuf + row * 512 + (kb ^ ((row & 7) << 4)));
      acc[mt][0] = __builtin_amdgcn_mfma_f32_16x16x32_bf16(a, bf0, acc[mt][0], 0, 0, 0);
      acc[mt][1] = __builtin_amdgcn_mfma_f32_16x16x32_bf16(a, bf1, acc[mt][1], 0, 0, 0);
    }
  }
}

// ---------------------------------------------------------------------------
// Fused GCN. Grid (16, 512): x = 64-vertex tile, y = batch. 512 thr = 8 waves,
// wave w owns output cols [32w, 32w+32). LDS: hA + hB, each 80x256 bf16 (40KB).
// Row r <-> vertex (v0 + r - 4) mod 1024; valid window shrinks 1/layer;
// out rows 4..67. Garbage rows quarantined outside the shrinking window.
// Buffer flow: stage->hA; L0: hA->hB; L1: hB->hA; L2: hA->hB; L3: hB->hA;
// head1: hA->hB; head2: hB->out.  ONE barrier per phase.
// ---------------------------------------------------------------------------
__global__ __launch_bounds__(512, 4)
void gcn_fused(const float* __restrict__ x, const short* __restrict__ ws,
               const float* __restrict__ b0p, const float* __restrict__ b1p,
               const float* __restrict__ b2p, const float* __restrict__ b3p,
               const float* __restrict__ hb1p, const float* __restrict__ hb2p,
               float* __restrict__ out){
  extern __shared__ char lds[];
  char* const hA = lds;
  char* const hB = lds + 40960;
  const int tid = threadIdx.x;
  const int lane = tid & 63, wid = tid >> 6;
  const int m15 = lane & 15, g = lane >> 4;
  const int n0 = wid * 32;
  const int b = blockIdx.y, v0 = blockIdx.x * 64;

  // ---- stage h0' into hA: temb chunks 0-15; chunk 16 = [cagg0,cagg1,c0,c1,0..];
  //      chunks 17-23 zero. (Layer-0 A-row = [temb, cagg, c] vs merged W0T.)
  {
    const short* tembp = ws + OFF_TEMB + b * 128;
    for (int task = tid; task < 72 * 16; task += 512){
      int r = task >> 4, ck = (task & 15) * 16;
      *(bf16x8*)(hA + r * 512 + (ck ^ ((r & 7) << 4))) =
          *(const bf16x8*)(tembp + (task & 15) * 8);
    }
    for (int task = tid; task < 80 * 8; task += 512){
      int r = task >> 3, q = task & 7;
      bf16x8 v = {0, 0, 0, 0, 0, 0, 0, 0};
      if (q == 0 && r < 72){
        const float* xb = x + b * 2048;
        int vm = (v0 + r - 5) & (NV - 1);
        int vc = (v0 + r - 4) & (NV - 1);
        int vp = (v0 + r - 3) & (NV - 1);
        float c0m = xb[vm * 2], c1m = xb[vm * 2 + 1];
        float c0c = xb[vc * 2], c1c = xb[vc * 2 + 1];
        float c0p = xb[vp * 2], c1p = xb[vp * 2 + 1];
        v[0] = f2bf((c0m + c0c + c0p) * (1.f / 3.f));
        v[1] = f2bf((c1m + c1c + c1p) * (1.f / 3.f));
        v[2] = f2bf(c0c);
        v[3] = f2bf(c1c);
      }
      *(bf16x8*)(hA + r * 512 + (((16 + q) * 16) ^ ((r & 7) << 4))) = v;
    }
  }
  __syncthreads();

  f32x4 acc[5][2];
  unsigned int hreg[5][2][2];   // packed bf16 h (residual), this wave's elems

  // ---- layer 0: ONE matmul (merged weights); h1 = silu(acc+b0) -> hB, hreg ----
  {
    const float bias0 = b0p[n0 + m15], bias1 = b0p[n0 + 16 + m15];
    #pragma unroll
    for (int mt = 0; mt < 5; ++mt){ acc[mt][0] = zero4(); acc[mt][1] = zero4(); }
    mm2<160>(hA, ws + OFF_W0T, m15, g, n0, acc);
    #pragma unroll
    for (int mt = 0; mt < 5; ++mt)
      #pragma unroll
      for (int nt = 0; nt < 2; ++nt){
        const float base = nt ? bias1 : bias0;
        const int row = mt * 16 + g * 4;
        const int cb = (n0 + nt * 16 + m15) * 2;
        unsigned short q0 = (unsigned short)f2bf(silu_f(acc[mt][nt][0] + base));
        unsigned short q1 = (unsigned short)f2bf(silu_f(acc[mt][nt][1] + base));
        unsigned short q2 = (unsigned short)f2bf(silu_f(acc[mt][nt][2] + base));
        unsigned short q3 = (unsigned short)f2bf(silu_f(acc[mt][nt][3] + base));
        *(short*)(hB + (row    ) * 512 + (cb ^ (((row    ) & 7) << 4))) = (short)q0;
        *(short*)(hB + (row + 1) * 512 + (cb ^ (((row + 1) & 7) << 4))) = (short)q1;
        *(short*)(hB + (row + 2) * 512 + (cb ^ (((row + 2) & 7) << 4))) = (short)q2;
        *(short*)(hB + (row + 3) * 512 + (cb ^ (((row + 3) & 7) << 4))) = (short)q3;
        hreg[mt][nt][0] = (unsigned int)q0 | ((unsigned int)q1 << 16);
        hreg[mt][nt][1] = (unsigned int)q2 | ((unsigned int)q3 << 16);
      }
  }
  __syncthreads();

  // ---- layers 1..3: h = silu(agg(h@W') + b + h); W' pre-scaled by 1/3;
  //      agg via in-reg shfl; residual from hreg; in->out buffer alternates ----
  #pragma unroll
  for (int L = 0; L < 3; ++L){
    const char* bin  = (L & 1) ? hA : hB;
    char*       bout = (L & 1) ? hB : hA;
    const short* Wt = ws + (L == 0 ? OFF_W1T : L == 1 ? OFF_W2T : OFF_W3T);
    const float* bp = (L == 0 ? b1p : L == 1 ? b2p : b3p);
    const float bias0 = bp[n0 + m15], bias1 = bp[n0 + 16 + m15];
    #pragma unroll
    for (int mt = 0; mt < 5; ++mt){ acc[mt][0] = zero4(); acc[mt][1] = zero4(); }
    mm2<256>(bin, Wt, m15, g, n0, acc);
    #pragma unroll
    for (int mt = 0; mt < 5; ++mt)
      #pragma unroll
      for (int nt = 0; nt < 2; ++nt){
        float a0 = acc[mt][nt][0], a1 = acc[mt][nt][1];
        float a2 = acc[mt][nt][2], a3 = acc[mt][nt][3];
        // row-1 for j=0 from lane+48; source pre-selects mt-1 at g==3
        float upv = (g == 3) ? acc[mt > 0 ? mt - 1 : 0][nt][3] : a3;
        float pm0 = __shfl(upv, (lane + 48) & 63);
        float dnv = (g == 0) ? acc[mt < 4 ? mt + 1 : 4][nt][0] : a0;
        float pp3 = __shfl(dnv, (lane + 16) & 63);
        const float base = nt ? bias1 : bias0;
        float r0 = bf2f((short)(hreg[mt][nt][0] & 0xffff));
        float r1 = bf2f((short)(hreg[mt][nt][0] >> 16));
        float r2 = bf2f((short)(hreg[mt][nt][1] & 0xffff));
        float r3 = bf2f((short)(hreg[mt][nt][1] >> 16));
        float s0 = pm0 + a0 + a1 + base + r0;
        float s1 = a0 + a1 + a2 + base + r1;
        float s2 = a1 + a2 + a3 + base + r2;
        float s3 = a2 + a3 + pp3 + base + r3;
        unsigned short q0 = (unsigned short)f2bf(silu_f(s0));
        unsigned short q1 = (unsigned short)f2bf(silu_f(s1));
        unsigned short q2 = (unsigned short)f2bf(silu_f(s2));
        unsigned short q3 = (unsigned short)f2bf(silu_f(s3));
        const int row = mt * 16 + g * 4;
        const int cb = (n0 + nt * 16 + m15) * 2;
        *(short*)(bout + (row    ) * 512 + (cb ^ (((row    ) & 7) << 4))) = (short)q0;
        *(short*)(bout + (row + 1) * 512 + (cb ^ (((row + 1) & 7) << 4))) = (short)q1;
        *(short*)(bout + (row + 2) * 512 + (cb ^ (((row + 2) & 7) << 4))) = (short)q2;
        *(short*)(bout + (row + 3) * 512 + (cb ^ (((row + 3) & 7) << 4))) = (short)q3;
        hreg[mt][nt][0] = (unsigned int)q0 | ((unsigned int)q1 << 16);
        hreg[mt][nt][1] = (unsigned int)q2 | ((unsigned int)q3 << 16);
      }
    __syncthreads();
  }
  // h4 now in hA.

  // ---- head part 1: u = silu(h4 @ hW1 + hb1): hA -> hB ----
  {
    const float bias0 = hb1p[n0 + m15], bias1 = hb1p[n0 + 16 + m15];
    #pragma unroll
    for (int mt = 0; mt < 5; ++mt){ acc[mt][0] = zero4(); acc[mt][1] = zero4(); }
    mm2<256>(hA, ws + OFF_HW1T, m15, g, n0, acc);
    #pragma unroll
    for (int mt = 0; mt < 5; ++mt)
      #pragma unroll
      for (int nt = 0; nt < 2; ++nt){
        const float base = nt ? bias1 : bias0;
        const int row = mt * 16 + g * 4;
        const int cb = (n0 + nt * 16 + m15) * 2;
        #pragma unroll
        for (int j = 0; j < 4; ++j){
          short q = f2bf(silu_f(acc[mt][nt][j] + base));
          *(short*)(hB + (row + j) * 512 + (cb ^ (((row + j) & 7) << 4))) = q;
        }
      }
    __syncthreads();
  }

  // ---- head part 2 (wave 0 only): out = u @ hW2 + hb2, rows 4..67 ----
  if (wid == 0){
    f32x4 a2[5];
    #pragma unroll
    for (int mt = 0; mt < 5; ++mt) a2[mt] = zero4();
    const short* wb = ws + OFF_HW2T + m15 * 256 + g * 8;
    #pragma unroll 2
    for (int ks = 0; ks < 8; ++ks){
      bf16x8 bfr = *(const bf16x8*)(wb + ks * 32);
      const int kb = ks * 64 + g * 16;
      #pragma unroll
      for (int mt = 0; mt < 5; ++mt){
        const int row = mt * 16 + m15;
        bf16x8 a = *(const bf16x8*)(hB + row * 512 + (kb ^ ((row & 7) << 4)));
        a2[mt] = __builtin_amdgcn_mfma_f32_16x16x32_bf16(a, bfr, a2[mt], 0, 0, 0);
      }
    }
    if (m15 < 2){
      float bias = hb2p[m15];
      #pragma unroll
      for (int mt = 0; mt < 5; ++mt)
        #pragma unroll
        for (int j = 0; j < 4; ++j){
          int row = mt * 16 + g * 4 + j;
          if (row >= 4 && row < 68)
            out[b * 2048 + (v0 + row - 4) * 2 + m15] = a2[mt][j] + bias;
        }
    }
  }
}

// ---------------------------------------------------------------------------
extern "C" void kernel_launch(void* const* d_in, const int* in_sizes, int n_in,
                              void* d_out, int out_size, void* d_ws, size_t ws_size,
                              hipStream_t stream){
  const float* x   = (const float*)d_in[0];
  const int*   t   = (const int*)  d_in[1];
  const float* tW  = (const float*)d_in[2];
  const float* tb  = (const float*)d_in[3];
  const float* W0  = (const float*)d_in[4];
  const float* b0  = (const float*)d_in[5];
  const float* W1  = (const float*)d_in[6];
  const float* b1  = (const float*)d_in[7];
  const float* W2  = (const float*)d_in[8];
  const float* b2  = (const float*)d_in[9];
  const float* W3  = (const float*)d_in[10];
  const float* b3  = (const float*)d_in[11];
  const float* res0= (const float*)d_in[12];
  const float* hW1 = (const float*)d_in[13];
  const float* hb1 = (const float*)d_in[14];
  const float* hW2 = (const float*)d_in[15];
  const float* hb2 = (const float*)d_in[16];
  short* ws  = (short*)d_ws;
  float* out = (float*)d_out;

  hipFuncSetAttribute((const void*)gcn_fused,
                      hipFuncAttributeMaxDynamicSharedMemorySize, 81920);

  prep_kernel<<<dim3((PREP_ELEMS + 255) / 256), dim3(256), 0, stream>>>(
      W0, res0, W1, W2, W3, hW1, hW2, ws);
  temb_kernel<<<dim3(512), dim3(128), 0, stream>>>(t, tW, tb, ws + OFF_TEMB);
  gcn_fused<<<dim3(16, 512), dim3(512), 81920, stream>>>(
      x, ws, b0, b1, b2, b3, hb1, hb2, out);
}

// Round 8
// 778.153 us; speedup vs baseline: 1.3940x; 1.3940x over previous
//
#include <hip/hip_runtime.h>
#include <hip/hip_bf16.h>

// ---------------------------------------------------------------------------
// DenoiseGCN fused kernel for MI355X (gfx950) — round 8.
// R7 post-mortem: hreg spilled again (708MB scratch writes) at the 8-wave
// 128-unified budget — REVERTED. Double-buffer kept: with hA/hB the residual
// is re-read from the READ-ONLY input buffer (bin) during the epilogue —
// no registers, no extra barrier, no hazard. 7 barriers total (R6 had 11),
// R6's register footprint (VGPR 64, zero spill).
// ---------------------------------------------------------------------------

typedef __attribute__((ext_vector_type(8))) short bf16x8;
typedef __attribute__((ext_vector_type(4))) float f32x4;

#define NV 1024

// ws element offsets (bf16 elements)
#define OFF_W0T   0        // [256][160] merged: k<128 temb (W0+res0), 128-129 W0c, 130-131 res0c
#define OFF_W1T   40960    // [256][256], pre-scaled by 1/3
#define OFF_W2T   106496   // pre-scaled by 1/3
#define OFF_W3T   172032   // pre-scaled by 1/3
#define OFF_HW1T  237568
#define OFF_HW2T  303104   // [16][256]
#define OFF_TEMB  307200   // [512][128]
#define PREP_ELEMS 307200

__device__ __forceinline__ float bf2f(short u){
  union { unsigned int i; float f; } v;
  v.i = ((unsigned int)(unsigned short)u) << 16;
  return v.f;
}
__device__ __forceinline__ short f2bf(float f){
  __hip_bfloat16 h = __float2bfloat16(f);
  return *reinterpret_cast<short*>(&h);
}
__device__ __forceinline__ float silu_f(float v){
  float e = __expf(-v);
  return v * __builtin_amdgcn_rcpf(1.f + e);
}
__device__ __forceinline__ f32x4 zero4(){ f32x4 z = {0.f,0.f,0.f,0.f}; return z; }

// ---------------------------------------------------------------------------
// prep: fp32 weights -> bf16, transposed to [N][K] (k contiguous) with pads.
// W0T merged (see header). W1..W3 pre-scaled by 1/3 (agg commutes with W).
// ---------------------------------------------------------------------------
__global__ void prep_kernel(const float* __restrict__ W0, const float* __restrict__ res0,
                            const float* __restrict__ W1, const float* __restrict__ W2,
                            const float* __restrict__ W3, const float* __restrict__ hW1,
                            const float* __restrict__ hW2, short* __restrict__ ws){
  int idx = blockIdx.x * 256 + threadIdx.x;
  if (idx >= PREP_ELEMS) return;
  float v = 0.f;
  if (idx < 40960){
    int n = idx / 160, k = idx - n * 160;
    if (k < 128)      v = W0[(k + 2) * 256 + n] + res0[(k + 2) * 256 + n];
    else if (k < 130) v = W0[(k - 128) * 256 + n];
    else if (k < 132) v = res0[(k - 130) * 256 + n];
  } else if (idx < 303104){
    int rem = idx - 40960;
    int seg = rem >> 16;
    int r2 = rem & 65535;
    int n = r2 >> 8, k = r2 & 255;
    const float* src = (seg == 0) ? W1 : (seg == 1) ? W2 : (seg == 2) ? W3 : hW1;
    v = src[k * 256 + n];
    if (seg < 3) v *= (1.f / 3.f);
  } else {
    int rem = idx - 303104;
    int n = rem >> 8, k = rem & 255;
    if (n < 2) v = hW2[k * 2 + n];
  }
  ws[idx] = f2bf(v);
}

// ---------------------------------------------------------------------------
// temb: silu(sinusoidal(t) @ time_W + time_b) per batch element -> bf16
// ---------------------------------------------------------------------------
__global__ void temb_kernel(const int* __restrict__ t, const float* __restrict__ tW,
                            const float* __restrict__ tb, short* __restrict__ temb){
  __shared__ float sc[128];
  int b = blockIdx.x, n = threadIdx.x;  // 128 threads
  float tv = (float)t[b];
  {
    int j = n & 63;
    float fr = __expf(-9.210340371976184f * (float)j * (1.f / 63.f));
    float ang = tv * fr;
    sc[n] = (n < 64) ? sinf(ang) : cosf(ang);
  }
  __syncthreads();
  float acc = tb[n];
  #pragma unroll 8
  for (int k = 0; k < 128; ++k) acc += sc[k] * tW[k * 128 + n];
  temb[b * 128 + n] = f2bf(silu_f(acc));
}

// ---------------------------------------------------------------------------
// mm2: acc[mt][nt] += hbuf[80 x KPAD] @ Wt^T for this wave's 2 col-tiles.
// A-frag: row=l&15 (+16*mt), k=(l>>4)*8+j.  B-frag: col=l&15, same k.
// C: col=l&15, row=(l>>4)*4+j.  hbuf rows are 512B, XOR-swizzled per 16B chunk.
// unroll 2: caps in-flight weight fragments (full unroll spilled — R4).
// ---------------------------------------------------------------------------
template<int KPAD>
__device__ __forceinline__ void mm2(const char* hbuf, const short* __restrict__ Wt,
                                    int m15, int g, int n0, f32x4 acc[5][2]){
  const short* wb = Wt + (n0 + m15) * KPAD + g * 8;
  #pragma unroll 2
  for (int ks = 0; ks < KPAD / 32; ++ks){
    bf16x8 bf0 = *(const bf16x8*)(wb + ks * 32);
    bf16x8 bf1 = *(const bf16x8*)(wb + 16 * KPAD + ks * 32);
    const int kb = ks * 64 + g * 16;
    #pragma unroll
    for (int mt = 0; mt < 5; ++mt){
      const int row = mt * 16 + m15;
      bf16x8 a = *(const bf16x8*)(hbuf + row * 512 + (kb ^ ((row & 7) << 4)));
      acc[mt][0] = __builtin_amdgcn_mfma_f32_16x16x32_bf16(a, bf0, acc[mt][0], 0, 0, 0);
      acc[mt][1] = __builtin_amdgcn_mfma_f32_16x16x32_bf16(a, bf1, acc[mt][1], 0, 0, 0);
    }
  }
}

// ---------------------------------------------------------------------------
// Fused GCN. Grid (16, 512): x = 64-vertex tile, y = batch. 512 thr = 8 waves,
// wave w owns output cols [32w, 32w+32). LDS: hA + hB, each 80x256 bf16 (40KB).
// Row r <-> vertex (v0 + r - 4) mod 1024; valid window shrinks 1/layer;
// out rows 4..67. Garbage rows quarantined outside the shrinking window.
// Buffer flow: stage->hA; L0: hA->hB; L1: hB->hA; L2: hA->hB; L3: hB->hA;
// head1: hA->hB; head2: hB->out. ONE barrier per phase; residual for layer L
// is re-read from bin (read-only during the phase — no hazard, no regs).
// ---------------------------------------------------------------------------
__global__ __launch_bounds__(512, 4)
void gcn_fused(const float* __restrict__ x, const short* __restrict__ ws,
               const float* __restrict__ b0p, const float* __restrict__ b1p,
               const float* __restrict__ b2p, const float* __restrict__ b3p,
               const float* __restrict__ hb1p, const float* __restrict__ hb2p,
               float* __restrict__ out){
  extern __shared__ char lds[];
  char* const hA = lds;
  char* const hB = lds + 40960;
  const int tid = threadIdx.x;
  const int lane = tid & 63, wid = tid >> 6;
  const int m15 = lane & 15, g = lane >> 4;
  const int n0 = wid * 32;
  const int b = blockIdx.y, v0 = blockIdx.x * 64;

  // ---- stage h0' into hA: temb chunks 0-15; chunk 16 = [cagg0,cagg1,c0,c1,0..];
  //      chunks 17-23 zero. (Layer-0 A-row = [temb, cagg, c] vs merged W0T.)
  {
    const short* tembp = ws + OFF_TEMB + b * 128;
    for (int task = tid; task < 72 * 16; task += 512){
      int r = task >> 4, ck = (task & 15) * 16;
      *(bf16x8*)(hA + r * 512 + (ck ^ ((r & 7) << 4))) =
          *(const bf16x8*)(tembp + (task & 15) * 8);
    }
    for (int task = tid; task < 80 * 8; task += 512){
      int r = task >> 3, q = task & 7;
      bf16x8 v = {0, 0, 0, 0, 0, 0, 0, 0};
      if (q == 0 && r < 72){
        const float* xb = x + b * 2048;
        int vm = (v0 + r - 5) & (NV - 1);
        int vc = (v0 + r - 4) & (NV - 1);
        int vp = (v0 + r - 3) & (NV - 1);
        float c0m = xb[vm * 2], c1m = xb[vm * 2 + 1];
        float c0c = xb[vc * 2], c1c = xb[vc * 2 + 1];
        float c0p = xb[vp * 2], c1p = xb[vp * 2 + 1];
        v[0] = f2bf((c0m + c0c + c0p) * (1.f / 3.f));
        v[1] = f2bf((c1m + c1c + c1p) * (1.f / 3.f));
        v[2] = f2bf(c0c);
        v[3] = f2bf(c1c);
      }
      *(bf16x8*)(hA + r * 512 + (((16 + q) * 16) ^ ((r & 7) << 4))) = v;
    }
  }
  __syncthreads();

  f32x4 acc[5][2];

  // ---- layer 0: ONE matmul (merged weights); h1 = silu(acc+b0): hA -> hB ----
  {
    const float bias0 = b0p[n0 + m15], bias1 = b0p[n0 + 16 + m15];
    #pragma unroll
    for (int mt = 0; mt < 5; ++mt){ acc[mt][0] = zero4(); acc[mt][1] = zero4(); }
    mm2<160>(hA, ws + OFF_W0T, m15, g, n0, acc);
    #pragma unroll
    for (int mt = 0; mt < 5; ++mt)
      #pragma unroll
      for (int nt = 0; nt < 2; ++nt){
        const float base = nt ? bias1 : bias0;
        const int row = mt * 16 + g * 4;
        const int cb = (n0 + nt * 16 + m15) * 2;
        #pragma unroll
        for (int j = 0; j < 4; ++j){
          short q = f2bf(silu_f(acc[mt][nt][j] + base));
          *(short*)(hB + (row + j) * 512 + (cb ^ (((row + j) & 7) << 4))) = q;
        }
      }
  }
  __syncthreads();

  // ---- layers 1..3: h = silu(agg(h@W') + b + h); W' pre-scaled by 1/3;
  //      agg via in-reg shfl; residual read from bin (read-only this phase) ----
  #pragma unroll
  for (int L = 0; L < 3; ++L){
    const char* bin  = (L & 1) ? hA : hB;
    char*       bout = (L & 1) ? hB : hA;
    const short* Wt = ws + (L == 0 ? OFF_W1T : L == 1 ? OFF_W2T : OFF_W3T);
    const float* bp = (L == 0 ? b1p : L == 1 ? b2p : b3p);
    const float bias0 = bp[n0 + m15], bias1 = bp[n0 + 16 + m15];
    #pragma unroll
    for (int mt = 0; mt < 5; ++mt){ acc[mt][0] = zero4(); acc[mt][1] = zero4(); }
    mm2<256>(bin, Wt, m15, g, n0, acc);
    #pragma unroll
    for (int mt = 0; mt < 5; ++mt)
      #pragma unroll
      for (int nt = 0; nt < 2; ++nt){
        float a0 = acc[mt][nt][0], a1 = acc[mt][nt][1];
        float a2 = acc[mt][nt][2], a3 = acc[mt][nt][3];
        // row-1 for j=0 from lane+48; source pre-selects mt-1 at g==3
        float upv = (g == 3) ? acc[mt > 0 ? mt - 1 : 0][nt][3] : a3;
        float pm0 = __shfl(upv, (lane + 48) & 63);
        float dnv = (g == 0) ? acc[mt < 4 ? mt + 1 : 4][nt][0] : a0;
        float pp3 = __shfl(dnv, (lane + 16) & 63);
        const float base = nt ? bias1 : bias0;
        const int row = mt * 16 + g * 4;
        const int cb = (n0 + nt * 16 + m15) * 2;
        float r0 = bf2f(*(const short*)(bin + (row    ) * 512 + (cb ^ (((row    ) & 7) << 4))));
        float r1 = bf2f(*(const short*)(bin + (row + 1) * 512 + (cb ^ (((row + 1) & 7) << 4))));
        float r2 = bf2f(*(const short*)(bin + (row + 2) * 512 + (cb ^ (((row + 2) & 7) << 4))));
        float r3 = bf2f(*(const short*)(bin + (row + 3) * 512 + (cb ^ (((row + 3) & 7) << 4))));
        float s0 = pm0 + a0 + a1 + base + r0;
        float s1 = a0 + a1 + a2 + base + r1;
        float s2 = a1 + a2 + a3 + base + r2;
        float s3 = a2 + a3 + pp3 + base + r3;
        *(short*)(bout + (row    ) * 512 + (cb ^ (((row    ) & 7) << 4))) = f2bf(silu_f(s0));
        *(short*)(bout + (row + 1) * 512 + (cb ^ (((row + 1) & 7) << 4))) = f2bf(silu_f(s1));
        *(short*)(bout + (row + 2) * 512 + (cb ^ (((row + 2) & 7) << 4))) = f2bf(silu_f(s2));
        *(short*)(bout + (row + 3) * 512 + (cb ^ (((row + 3) & 7) << 4))) = f2bf(silu_f(s3));
      }
    __syncthreads();
  }
  // h4 now in hA.

  // ---- head part 1: u = silu(h4 @ hW1 + hb1): hA -> hB ----
  {
    const float bias0 = hb1p[n0 + m15], bias1 = hb1p[n0 + 16 + m15];
    #pragma unroll
    for (int mt = 0; mt < 5; ++mt){ acc[mt][0] = zero4(); acc[mt][1] = zero4(); }
    mm2<256>(hA, ws + OFF_HW1T, m15, g, n0, acc);
    #pragma unroll
    for (int mt = 0; mt < 5; ++mt)
      #pragma unroll
      for (int nt = 0; nt < 2; ++nt){
        const float base = nt ? bias1 : bias0;
        const int row = mt * 16 + g * 4;
        const int cb = (n0 + nt * 16 + m15) * 2;
        #pragma unroll
        for (int j = 0; j < 4; ++j){
          short q = f2bf(silu_f(acc[mt][nt][j] + base));
          *(short*)(hB + (row + j) * 512 + (cb ^ (((row + j) & 7) << 4))) = q;
        }
      }
    __syncthreads();
  }

  // ---- head part 2 (wave 0 only): out = u @ hW2 + hb2, rows 4..67 ----
  if (wid == 0){
    f32x4 a2[5];
    #pragma unroll
    for (int mt = 0; mt < 5; ++mt) a2[mt] = zero4();
    const short* wb = ws + OFF_HW2T + m15 * 256 + g * 8;
    #pragma unroll 2
    for (int ks = 0; ks < 8; ++ks){
      bf16x8 bfr = *(const bf16x8*)(wb + ks * 32);
      const int kb = ks * 64 + g * 16;
      #pragma unroll
      for (int mt = 0; mt < 5; ++mt){
        const int row = mt * 16 + m15;
        bf16x8 a = *(const bf16x8*)(hB + row * 512 + (kb ^ ((row & 7) << 4)));
        a2[mt] = __builtin_amdgcn_mfma_f32_16x16x32_bf16(a, bfr, a2[mt], 0, 0, 0);
      }
    }
    if (m15 < 2){
      float bias = hb2p[m15];
      #pragma unroll
      for (int mt = 0; mt < 5; ++mt)
        #pragma unroll
        for (int j = 0; j < 4; ++j){
          int row = mt * 16 + g * 4 + j;
          if (row >= 4 && row < 68)
            out[b * 2048 + (v0 + row - 4) * 2 + m15] = a2[mt][j] + bias;
        }
    }
  }
}

// ---------------------------------------------------------------------------
extern "C" void kernel_launch(void* const* d_in, const int* in_sizes, int n_in,
                              void* d_out, int out_size, void* d_ws, size_t ws_size,
                              hipStream_t stream){
  const float* x   = (const float*)d_in[0];
  const int*   t   = (const int*)  d_in[1];
  const float* tW  = (const float*)d_in[2];
  const float* tb  = (const float*)d_in[3];
  const float* W0  = (const float*)d_in[4];
  const float* b0  = (const float*)d_in[5];
  const float* W1  = (const float*)d_in[6];
  const float* b1  = (const float*)d_in[7];
  const float* W2  = (const float*)d_in[8];
  const float* b2  = (const float*)d_in[9];
  const float* W3  = (const float*)d_in[10];
  const float* b3  = (const float*)d_in[11];
  const float* res0= (const float*)d_in[12];
  const float* hW1 = (const float*)d_in[13];
  const float* hb1 = (const float*)d_in[14];
  const float* hW2 = (const float*)d_in[15];
  const float* hb2 = (const float*)d_in[16];
  short* ws  = (short*)d_ws;
  float* out = (float*)d_out;

  hipFuncSetAttribute((const void*)gcn_fused,
                      hipFuncAttributeMaxDynamicSharedMemorySize, 81920);

  prep_kernel<<<dim3((PREP_ELEMS + 255) / 256), dim3(256), 0, stream>>>(
      W0, res0, W1, W2, W3, hW1, hW2, ws);
  temb_kernel<<<dim3(512), dim3(128), 0, stream>>>(t, tW, tb, ws + OFF_TEMB);
  gcn_fused<<<dim3(16, 512), dim3(512), 81920, stream>>>(
      x, ws, b0, b1, b2, b3, hb1, hb2, out);
}